// Round 4
// baseline (2604.806 us; speedup 1.0000x reference)
//
#include <hip/hip_runtime.h>
#include <hip/hip_bf16.h>

// QLSTM island-MFMA: T=512, B=256, D=128, H=256, P=128, GAMMA=1.
// 16 workgroups ("islands") x 512 threads; island g owns batch rows [16g,16g+16).
// Per step: dist GEMM [16x384]x[384x128] -> k, gates GEMM [16x128]x[128x1024],
// cell update fully in registers. Weights/protos register-resident per wave.
// MFMA layouts (verified in R2/R3 sx_kernel): A[m=lane&15][k=quad*8+j],
// B passed as [n=lane&15][k=quad*8+j], C/D col=lane&15, row=quad*4+reg.

#define TT 512
#define BB 256
#define DD 128
#define HH 256
#define PP 128
#define DHH 384

typedef _Float16 h4 __attribute__((ext_vector_type(4)));
typedef _Float16 h8 __attribute__((ext_vector_type(8)));
typedef float f4v __attribute__((ext_vector_type(4)));

__device__ __forceinline__ float sigm_f(float x) { return 1.f / (1.f + __expf(-x)); }
__device__ __forceinline__ float tanh_f(float x) { return 1.f - 2.f / (1.f + __expf(2.f * x)); }

__global__ __launch_bounds__(512) void qlstm_kernel(
    const float* __restrict__ x, const float* __restrict__ proto,
    const float* __restrict__ Wf, const float* __restrict__ bfv,
    const float* __restrict__ Wi, const float* __restrict__ biv,
    const float* __restrict__ Wg, const float* __restrict__ bgv,
    const float* __restrict__ Wo, const float* __restrict__ bov,
    float* __restrict__ out) {
  const int g = blockIdx.x;
  const int tid = threadIdx.x;
  const int w = tid >> 6;          // wave 0..7
  const int lane = tid & 63;
  const int col = lane & 15;
  const int quad = lane >> 4;

  // LDS: combined [16 rows][392 halves] (k-dims: 0..128 = x_t, 128..384 = hx, +8 pad)
  __shared__ __align__(16) _Float16 comb[16 * 392];
  __shared__ __align__(16) _Float16 kbuf[16 * 136];   // k [16 rows][128 p +8 pad]
  __shared__ __align__(16) float hpart[16 * 8];       // ||hx||^2 partials [row][wave]
  __shared__ float xn[16];                            // ||x_t[row]||^2

  // ---- proto B-frags (dist GEMM), scaled by -2, f16; wave w owns p in [16w,16w+16) ----
  const int p0 = 16 * w;
  h8 pb[12];
  float pn = 0.f;
#pragma unroll
  for (int c = 0; c < 12; ++c) {
    const float* src = proto + (size_t)(p0 + col) * DHH + c * 32 + quad * 8;
    float4 a = *(const float4*)src;
    float4 b2 = *(const float4*)(src + 4);
    pn += a.x * a.x + a.y * a.y + a.z * a.z + a.w * a.w;
    pn += b2.x * b2.x + b2.y * b2.y + b2.z * b2.z + b2.w * b2.w;
    h8 v;
    v[0] = (_Float16)(-2.f * a.x);  v[1] = (_Float16)(-2.f * a.y);
    v[2] = (_Float16)(-2.f * a.z);  v[3] = (_Float16)(-2.f * a.w);
    v[4] = (_Float16)(-2.f * b2.x); v[5] = (_Float16)(-2.f * b2.y);
    v[6] = (_Float16)(-2.f * b2.z); v[7] = (_Float16)(-2.f * b2.w);
    pb[c] = v;
  }
  pn += __shfl_xor(pn, 16);   // sum over quads (k-dim split)
  pn += __shfl_xor(pn, 32);

  // ---- gate weight B-frags (f16) + biases; wave w owns h in [32w,32w+32) ----
  h8 wb[4][2][4];  // [gate f,i,g,o][n-tile][k-chunk]
  float bias[4][2];
  {
    const float* Wm[4] = {Wf, Wi, Wg, Wo};
    const float* Bm[4] = {bfv, biv, bgv, bov};
#pragma unroll
    for (int gi = 0; gi < 4; ++gi) {
#pragma unroll
      for (int nt = 0; nt < 2; ++nt) {
        const int h0 = 32 * w + nt * 16;
        bias[gi][nt] = Bm[gi][h0 + col];
#pragma unroll
        for (int c = 0; c < 4; ++c) {
          const float* sw = Wm[gi] + (size_t)(h0 + col) * PP + c * 32 + quad * 8;
          float4 a = *(const float4*)sw;
          float4 b2 = *(const float4*)(sw + 4);
          h8 v;
          v[0] = (_Float16)a.x;  v[1] = (_Float16)a.y;  v[2] = (_Float16)a.z;  v[3] = (_Float16)a.w;
          v[4] = (_Float16)b2.x; v[5] = (_Float16)b2.y; v[6] = (_Float16)b2.z; v[7] = (_Float16)b2.w;
          wb[gi][nt][c] = v;
        }
      }
    }
  }

  // ---- init LDS: zero hx section + hpart; stage x_0 + xn_0 ----
  {
    const int r = tid >> 5;
    const int o = (tid & 31) * 8;
    h8 z = {};
    *(h8*)(comb + r * 392 + 128 + o) = z;
  }
  if (tid < 128) hpart[tid] = 0.f;
  {
    const int r = tid >> 5;
    const int cc = tid & 31;
    float4 v = *(const float4*)(x + ((size_t)0 * BB + 16 * g + r) * DD + cc * 4);
    float sq = v.x * v.x + v.y * v.y + v.z * v.z + v.w * v.w;
    sq += __shfl_xor(sq, 1);  sq += __shfl_xor(sq, 2);  sq += __shfl_xor(sq, 4);
    sq += __shfl_xor(sq, 8);  sq += __shfl_xor(sq, 16);
    if (cc == 0) xn[r] = sq;
    h4 hv;
    hv[0] = (_Float16)v.x; hv[1] = (_Float16)v.y; hv[2] = (_Float16)v.z; hv[3] = (_Float16)v.w;
    *(h4*)(comb + r * 392 + cc * 4) = hv;
  }
  __syncthreads();

  float cx[2][4];
  float hx_reg[2][4];
#pragma unroll
  for (int nt = 0; nt < 2; ++nt)
#pragma unroll
    for (int rr = 0; rr < 4; ++rr) { cx[nt][rr] = 0.f; hx_reg[nt][rr] = 0.f; }

  for (int t = 0; t < TT; ++t) {
    // ---- prefetch x_{t+1} into registers (latency hidden by both GEMMs) ----
    const int xr = tid >> 5;
    const int xc = tid & 31;
    float4 xpre;
    if (t + 1 < TT)
      xpre = *(const float4*)(x + ((size_t)(t + 1) * BB + 16 * g + xr) * DD + xc * 4);

    // ---- phase A: dist GEMM, 12 k-chunks, 2 interleaved acc chains ----
    f4v accE = {0.f, 0.f, 0.f, 0.f};
    f4v accO = {0.f, 0.f, 0.f, 0.f};
#pragma unroll
    for (int c = 0; c < 12; c += 2) {
      h8 a0 = *(const h8*)(comb + col * 392 + c * 32 + quad * 8);
      h8 a1 = *(const h8*)(comb + col * 392 + (c + 1) * 32 + quad * 8);
      accE = __builtin_amdgcn_mfma_f32_16x16x32_f16(a0, pb[c], accE, 0, 0, 0);
      accO = __builtin_amdgcn_mfma_f32_16x16x32_f16(a1, pb[c + 1], accO, 0, 0, 0);
    }
    // cnorm[b] = ||x_t[b]||^2 + ||hx[b]||^2 ; computed at lane row=col, moved via shfl
    float hn;
    {
      f4v h0 = *(const f4v*)(hpart + col * 8);
      f4v h1 = *(const f4v*)(hpart + col * 8 + 4);
      hn = h0[0] + h0[1] + h0[2] + h0[3] + h1[0] + h1[1] + h1[2] + h1[3];
    }
    const float cnl = hn + xn[col];
    f4v acc = accE + accO;
#pragma unroll
    for (int rr = 0; rr < 4; ++rr) {
      const float cn = __shfl(cnl, quad * 4 + rr);     // lane (quad*4+rr) holds row's cnorm
      const float d2 = acc[rr] + pn + cn;
      const float kk = __expf(-d2);
      kbuf[(quad * 4 + rr) * 136 + p0 + col] = (_Float16)kk;
    }
    __syncthreads();  // barrier 1: kbuf ready; comb/hpart/xn reads done

    // ---- phase B: gates GEMM ----
    h8 ka[4];
#pragma unroll
    for (int c = 0; c < 4; ++c)
      ka[c] = *(const h8*)(kbuf + col * 136 + c * 32 + quad * 8);
    f4v gacc[4][2];
#pragma unroll
    for (int gi = 0; gi < 4; ++gi)
#pragma unroll
      for (int nt = 0; nt < 2; ++nt) gacc[gi][nt] = f4v{0.f, 0.f, 0.f, 0.f};
#pragma unroll
    for (int c = 0; c < 4; ++c)
#pragma unroll
      for (int gi = 0; gi < 4; ++gi)
#pragma unroll
        for (int nt = 0; nt < 2; ++nt)
          gacc[gi][nt] = __builtin_amdgcn_mfma_f32_16x16x32_f16(ka[c], wb[gi][nt][c], gacc[gi][nt], 0, 0, 0);

    // ---- cell update, fully in registers (lane owns 8 (b,h) pairs) ----
    float hnp[4] = {0.f, 0.f, 0.f, 0.f};
#pragma unroll
    for (int nt = 0; nt < 2; ++nt) {
      const int hcol = 32 * w + nt * 16 + col;
#pragma unroll
      for (int rr = 0; rr < 4; ++rr) {
        const float pf = gacc[0][nt][rr] + bias[0][nt];
        const float pi = gacc[1][nt][rr] + bias[1][nt];
        const float pg = gacc[2][nt][rr] + bias[2][nt];
        const float po = gacc[3][nt][rr] + bias[3][nt];
        const float f_ = sigm_f(pf);
        const float i_ = sigm_f(pi);
        const float g_ = tanh_f(pg);
        const float o_ = sigm_f(po);
        const float c_ = fmaf(f_, cx[nt][rr], i_ * g_);
        cx[nt][rr] = c_;
        const float hh = o_ * tanh_f(c_);
        hx_reg[nt][rr] = hh;
        const int b = quad * 4 + rr;
        out[((size_t)t * BB + 16 * g + b) * HH + hcol] = hh;
        comb[b * 392 + 128 + hcol] = (_Float16)hh;
        hnp[rr] = fmaf(hh, hh, hnp[rr]);
      }
    }
    // reduce ||hx||^2 partial over the 16 cols, write per-wave partial
#pragma unroll
    for (int rr = 0; rr < 4; ++rr) {
      float s = hnp[rr];
      s += __shfl_xor(s, 1); s += __shfl_xor(s, 2);
      s += __shfl_xor(s, 4); s += __shfl_xor(s, 8);
      hnp[rr] = s;
    }
    if (col == 0) {
#pragma unroll
      for (int rr = 0; rr < 4; ++rr) hpart[(quad * 4 + rr) * 8 + w] = hnp[rr];
    }
    // stage x_{t+1} (comb x-section free: phase A reads finished before barrier 1)
    if (t + 1 < TT) {
      float sq = xpre.x * xpre.x + xpre.y * xpre.y + xpre.z * xpre.z + xpre.w * xpre.w;
      sq += __shfl_xor(sq, 1);  sq += __shfl_xor(sq, 2);  sq += __shfl_xor(sq, 4);
      sq += __shfl_xor(sq, 8);  sq += __shfl_xor(sq, 16);
      if (xc == 0) xn[xr] = sq;
      h4 hv;
      hv[0] = (_Float16)xpre.x; hv[1] = (_Float16)xpre.y;
      hv[2] = (_Float16)xpre.z; hv[3] = (_Float16)xpre.w;
      *(h4*)(comb + xr * 392 + xc * 4) = hv;
    }
    __syncthreads();  // barrier 2: end of step
  }

  // ---- final hx, cx ----
  const size_t base = (size_t)TT * BB * HH;
#pragma unroll
  for (int nt = 0; nt < 2; ++nt) {
    const int hcol = 32 * w + nt * 16 + col;
#pragma unroll
    for (int rr = 0; rr < 4; ++rr) {
      const int b = 16 * g + quad * 4 + rr;
      out[base + (size_t)b * HH + hcol] = hx_reg[nt][rr];
      out[base + (size_t)BB * HH + (size_t)b * HH + hcol] = cx[nt][rr];
    }
  }
}

extern "C" void kernel_launch(void* const* d_in, const int* in_sizes, int n_in,
                              void* d_out, int out_size, void* d_ws, size_t ws_size,
                              hipStream_t stream) {
  const float* x     = (const float*)d_in[0];
  const float* proto = (const float*)d_in[1];
  const float* Wf = (const float*)d_in[2];
  const float* bf = (const float*)d_in[3];
  const float* Wi = (const float*)d_in[4];
  const float* bi = (const float*)d_in[5];
  const float* Wg = (const float*)d_in[6];
  const float* bg = (const float*)d_in[7];
  const float* Wo = (const float*)d_in[8];
  const float* bo = (const float*)d_in[9];
  float* out = (float*)d_out;

  qlstm_kernel<<<16, 512, 0, stream>>>(x, proto, Wf, bf, Wi, bi, Wg, bg, Wo, bo, out);
}